// Round 4
// baseline (2865.845 us; speedup 1.0000x reference)
//
#include <hip/hip_runtime.h>
#include <stdint.h>

#define NBATCH 128
#define NT     64
#define OBD    32
#define ACD    8
#define LDIM   128
#define HDIM   256

typedef _Float16 h2 __attribute__((ext_vector_type(2)));
typedef float    f4 __attribute__((ext_vector_type(4)));

#if defined(__has_builtin)
#  if __has_builtin(__builtin_amdgcn_fdot2)
#    define HAVE_FDOT2 1
#  endif
#endif

__device__ __forceinline__ float dot2f(h2 a, h2 b, float c) {
#ifdef HAVE_FDOT2
  return __builtin_amdgcn_fdot2(a, b, c, false);
#else
  return c + (float)a[0] * (float)b[0] + (float)a[1] * (float)b[1];
#endif
}

__device__ __forceinline__ h2 pkh(float a, float b) {
  h2 r; r[0] = (_Float16)a; r[1] = (_Float16)b; return r;
}

__device__ __forceinline__ h2 bch(float x) { return __builtin_bit_cast(h2, x); }

__device__ __forceinline__ float sigmf(float x) { return 1.0f / (1.0f + expf(-x)); }

#define DOT4(W, I, Q) \
    a0 = dot2f(W[4*(I)+0], bch(Q.x), a0); \
    a1 = dot2f(W[4*(I)+1], bch(Q.y), a1); \
    a2 = dot2f(W[4*(I)+2], bch(Q.z), a2); \
    a3 = dot2f(W[4*(I)+3], bch(Q.w), a3);

// 1024 threads: H-stages row p=t>>2 (K 4-way, qs=t&3); L-stages row r=t>>3
// (K 8-way, es=t&7). Per-thread persistent weights = 72 regs -> fits the
// 128-VGPR budget the compiler enforces at >=8 waves/block (r2/r3: 168 regs
// spilled -> 50 MB scratch traffic, VALUBusy 18%). All shfl_xor reductions.
// LDS activation buffers padded so K-slice bases hit distinct banks.
__global__ __launch_bounds__(1024)
void ode_rnn_kernel(const float* __restrict__ ob,   const float* __restrict__ acs,
                    const float* __restrict__ times,
                    const float* __restrict__ We0,  const float* __restrict__ be0,
                    const float* __restrict__ We1,  const float* __restrict__ be1,
                    const float* __restrict__ Wd0,  const float* __restrict__ bd0,
                    const float* __restrict__ Wd1,  const float* __restrict__ bd1,
                    const float* __restrict__ Wd2,  const float* __restrict__ bd2,
                    const float* __restrict__ Wo0,  const float* __restrict__ bo0,
                    const float* __restrict__ Wo1,  const float* __restrict__ bo1,
                    const float* __restrict__ Wih,  const float* __restrict__ Whh,
                    const float* __restrict__ bih,  const float* __restrict__ bn,
                    float* __restrict__ out)
{
  const int t  = threadIdx.x;
  const int b  = blockIdx.x;
  const int p  = t >> 2;            // 0..255  H-stage row
  const int qs = t & 3;             // K-quarter
  const int r  = t >> 3;            // 0..127  L-stage row
  const int es = t & 7;             // K-eighth
  const int o  = t >> 5;            // 0..31   decoder out row
  const int s5 = t & 31;            // decoder K-slice
  const int gr = t >> 1;            // 0..511  GRU row (active < 384)
  const int kh = t & 1;             // GRU K-half

  __shared__ __align__(16) float s_lat[LDIM];
  __shared__ __align__(16) float s_k[5][LDIM];
  __shared__ __align__(16) float s_gr[LDIM];
  __shared__ __align__(16) float s_gz[LDIM];
  __shared__ __align__(16) float s_gin[LDIM];
  __shared__ __align__(16) float s_ghn[LDIM];
  __shared__ __align__(16) float s_tmp[HDIM];
  __shared__ __align__(16) float s_obs[OBD];
  __shared__ __align__(16) float s_times[NT];
  __shared__ __align__(16) float s_acs[NT * ACD];
  __shared__ __align__(16) h2    s_in16[80];    // 4 slices x (16 data + 4 pad)
  __shared__ __align__(16) h2    s_a16[144];    // 4 slices x (32 data + 4 pad)
  __shared__ __align__(16) h2    s_b16[160];    // 8 slices x (16 data + 4 pad)

#define W16(i) ((i) + (((i) >> 4) << 2))
#define WA(i)  ((i) + (((i) >> 5) << 2))
#define WB(i)  ((i) + (((i) >> 4) << 2))

  // ---- per-thread f16 weight fragments (one-time load, live in VGPRs) ----
  h2 w0[16], w1[32], w2[16], q1[4];
  {
    const float2* pp = (const float2*)(Wd0 + p * LDIM + qs * 32);
#pragma unroll
    for (int i = 0; i < 16; ++i) { float2 v = pp[i]; w0[i] = pkh(v.x, v.y); }
  }
  {
    const float2* pp = (const float2*)(Wd1 + p * HDIM + qs * 64);
#pragma unroll
    for (int i = 0; i < 32; ++i) { float2 v = pp[i]; w1[i] = pkh(v.x, v.y); }
  }
  {
    const float2* pp = (const float2*)(Wd2 + r * HDIM + es * 32);
#pragma unroll
    for (int i = 0; i < 16; ++i) { float2 v = pp[i]; w2[i] = pkh(v.x, v.y); }
  }
  {
    const float2* pp = (const float2*)(Wo1 + o * HDIM + s5 * 8);
#pragma unroll
    for (int i = 0; i < 4; ++i) { float2 v = pp[i]; q1[i] = pkh(v.x, v.y); }
  }
  float wi[4];
  if (gr < 3 * LDIM) {
#pragma unroll
    for (int j = 0; j < 4; ++j) wi[j] = Wih[gr * ACD + kh * 4 + j];
  } else {
#pragma unroll
    for (int j = 0; j < 4; ++j) wi[j] = 0.0f;
  }

  const float bb0 = bd0[p];
  const float bb1 = bd1[p];
  const float bb2 = bd2[r];
  const float rb0 = bo0[p];
  const float rb1 = bo1[o];
  const float gA  = (gr < 3 * LDIM) ? bih[gr] : 0.0f;
  const float bnr = (t < LDIM) ? bn[t] : 0.0f;

  // ---- one Dopri5 substep; entry: s_in16 = packed lat, s_lat = lat ----
  auto substep = [&](float hs) {
#pragma unroll
    for (int s = 0; s < 6; ++s) {
      float a0, a1, a2, a3, v;
      // stage 1: h1 = relu(Wd0 @ z + bd0)
      a0 = a1 = a2 = a3 = 0.0f;
      {
        const f4* src = ((const f4*)s_in16) + qs * 5;
#pragma unroll
        for (int i = 0; i < 4; ++i) { f4 q = src[i]; DOT4(w0, i, q) }
      }
      v = (a0 + a1) + (a2 + a3);
      v += __shfl_xor(v, 1);
      v += __shfl_xor(v, 2);
      v = fmaxf(v + bb0, 0.0f);
      { float ov = __shfl_xor(v, 4); if ((t & 7) == 0) s_a16[WA(t >> 3)] = pkh(v, ov); }
      __syncthreads();
      // stage 2: h2 = relu(Wd1 @ h1 + bd1)
      a0 = a1 = a2 = a3 = 0.0f;
      {
        const f4* src = ((const f4*)s_a16) + qs * 9;
#pragma unroll
        for (int i = 0; i < 8; ++i) { f4 q = src[i]; DOT4(w1, i, q) }
      }
      v = (a0 + a1) + (a2 + a3);
      v += __shfl_xor(v, 1);
      v += __shfl_xor(v, 2);
      v = fmaxf(v + bb1, 0.0f);
      { float ov = __shfl_xor(v, 4); if ((t & 7) == 0) s_b16[WB(t >> 3)] = pkh(v, ov); }
      __syncthreads();
      // stage 3: k_s = Wd2 @ h2 + bd2, fused RK tail
      a0 = a1 = a2 = a3 = 0.0f;
      {
        const f4* src = ((const f4*)s_b16) + es * 5;
#pragma unroll
        for (int i = 0; i < 4; ++i) { f4 q = src[i]; DOT4(w2, i, q) }
      }
      v = (a0 + a1) + (a2 + a3);
      v += __shfl_xor(v, 1);
      v += __shfl_xor(v, 2);
      v += __shfl_xor(v, 4);
      float kv = v + bb2;
      if (s < 5 && es == 0) s_k[s][r] = kv;
      float base = s_lat[r];
      float z;
      if (s == 0)
        z = base + hs * (0.2f * kv);
      else if (s == 1)
        z = base + hs * ((3.0f/40.0f)*s_k[0][r] + (9.0f/40.0f)*kv);
      else if (s == 2)
        z = base + hs * ((44.0f/45.0f)*s_k[0][r] - (56.0f/15.0f)*s_k[1][r]
                       + (32.0f/9.0f)*kv);
      else if (s == 3)
        z = base + hs * ((19372.0f/6561.0f)*s_k[0][r] - (25360.0f/2187.0f)*s_k[1][r]
                       + (64448.0f/6561.0f)*s_k[2][r] - (212.0f/729.0f)*kv);
      else if (s == 4)
        z = base + hs * ((9017.0f/3168.0f)*s_k[0][r] - (355.0f/33.0f)*s_k[1][r]
                       + (46732.0f/5247.0f)*s_k[2][r] + (49.0f/176.0f)*s_k[3][r]
                       - (5103.0f/18656.0f)*kv);
      else
        z = base + hs * ((35.0f/384.0f)*s_k[0][r] + (500.0f/1113.0f)*s_k[2][r]
                       + (125.0f/192.0f)*s_k[3][r] - (2187.0f/6784.0f)*s_k[4][r]
                       + (11.0f/84.0f)*kv);
      { float ov = __shfl_xor(z, 8); if ((t & 15) == 0) s_in16[W16(t >> 4)] = pkh(z, ov); }
      if (s == 5 && es == 0) s_lat[r] = z;
      __syncthreads();
    }
  };

  // ---- GRU (fp32; Whh streamed from L2; rows 2-way K-split) ----
  auto gru = [&](int ts) {
    __syncthreads();                 // publish s_lat
    float vi = 0.0f, vh = 0.0f;
    if (gr < 3 * LDIM) {
      const float* xa = s_acs + ts * ACD + kh * 4;
#pragma unroll
      for (int j = 0; j < 4; ++j) vi += wi[j] * xa[j];
      const f4* wh = (const f4*)(Whh + gr * LDIM + kh * 64);
      const f4* xl = ((const f4*)s_lat) + kh * 16;
#pragma unroll
      for (int k2 = 0; k2 < 16; ++k2) {
        f4 w = wh[k2], x = xl[k2];
        vh += w.x*x.x + w.y*x.y + w.z*x.z + w.w*x.w;
      }
    }
    vi += __shfl_xor(vi, 1);
    vh += __shfl_xor(vh, 1);
    if (gr < 3 * LDIM && kh == 0) {
      if (gr < LDIM)           s_gr[gr] = vi + gA + vh;
      else if (gr < 2 * LDIM)  s_gz[gr - LDIM] = vi + gA + vh;
      else                   { s_gin[gr - 2*LDIM] = vi + gA; s_ghn[gr - 2*LDIM] = vh; }
    }
    __syncthreads();
    if (t < LDIM) {
      float rg = sigmf(s_gr[t]);
      float zg = sigmf(s_gz[t]);
      float ng = tanhf(s_gin[t] + rg * (s_ghn[t] + bnr));
      float y  = (1.0f - zg) * ng + zg * s_lat[t];
      s_lat[t] = y;
      float ov = __shfl_xor(y, 1);
      if (!(t & 1)) s_in16[W16(t >> 1)] = pkh(y, ov);
    }
  };

  // ---- decoder: Wo0 streamed f32 (L2-resident, 64 uses); Wo1 in regs ----
  auto decode = [&](int ts) {
    __syncthreads();                 // publish s_in16 / s_lat
    float acc = 0.0f;
    {
      const f4* wr = (const f4*)(Wo0 + p * LDIM + qs * 32);
      const f4* xl = ((const f4*)s_lat) + qs * 8;
#pragma unroll
      for (int k2 = 0; k2 < 8; ++k2) {
        f4 w = wr[k2], x = xl[k2];
        acc += w.x*x.x + w.y*x.y + w.z*x.z + w.w*x.w;
      }
    }
    acc += __shfl_xor(acc, 1);
    acc += __shfl_xor(acc, 2);
    acc = fmaxf(acc + rb0, 0.0f);
    { float ov = __shfl_xor(acc, 4); if ((t & 7) == 0) s_a16[WA(t >> 3)] = pkh(acc, ov); }
    __syncthreads();
    float a0 = 0, a1 = 0, a2 = 0, a3 = 0;
    {
      const f4 q = *(((const f4*)s_a16) + s5 + (s5 >> 3));
      a0 = dot2f(q1[0], bch(q.x), a0);
      a1 = dot2f(q1[1], bch(q.y), a1);
      a2 = dot2f(q1[2], bch(q.z), a2);
      a3 = dot2f(q1[3], bch(q.w), a3);
    }
    float v = (a0 + a1) + (a2 + a3);
    v += __shfl_xor(v, 1);
    v += __shfl_xor(v, 2);
    v += __shfl_xor(v, 4);
    v += __shfl_xor(v, 8);
    v += __shfl_xor(v, 16);
    if (s5 == 0) out[((size_t)b * NT + ts) * OBD + o] = v + rb1;
    __syncthreads();                 // protect s_a16 / s_lat for next phase
  };

  // ================= init + encoder =================
  if (t < OBD) s_obs[t] = ob[b * OBD + t];
  if (t < NT)  s_times[t] = times[b * NT + t];
  if (t < NT * ACD) s_acs[t] = acs[(size_t)b * NT * ACD + t];
  __syncthreads();
  if (t < HDIM) {
    float acc = be0[t];
    const float* wr = We0 + t * OBD;
#pragma unroll
    for (int j = 0; j < OBD; ++j) acc += wr[j] * s_obs[j];
    s_tmp[t] = fmaxf(acc, 0.0f);
  }
  __syncthreads();
  {
    const f4* wr = (const f4*)(We1 + r * HDIM + es * 32);
    const f4* xs = ((const f4*)s_tmp) + es * 8;
    float acc = 0.0f;
#pragma unroll
    for (int k = 0; k < 8; ++k) {
      f4 w = wr[k], x = xs[k];
      acc += w.x*x.x + w.y*x.y + w.z*x.z + w.w*x.w;
    }
    acc += __shfl_xor(acc, 1);
    acc += __shfl_xor(acc, 2);
    acc += __shfl_xor(acc, 4);
    if (es == 0) s_lat[r] = acc + be1[r];
  }

  // ================= time loop =================
  gru(0);
  decode(0);

#pragma unroll 1
  for (int ts = 1; ts < NT; ++ts) {
    float hs = 0.25f * (s_times[ts] - s_times[ts - 1]);
#pragma unroll 1
    for (int su = 0; su < 4; ++su) substep(hs);
    gru(ts);
    decode(ts);
  }
}

extern "C" void kernel_launch(void* const* d_in, const int* in_sizes, int n_in,
                              void* d_out, int out_size, void* d_ws, size_t ws_size,
                              hipStream_t stream) {
  (void)in_sizes; (void)n_in; (void)d_ws; (void)ws_size; (void)out_size;
  const float* ob    = (const float*)d_in[0];
  const float* acs   = (const float*)d_in[1];
  const float* times = (const float*)d_in[2];
  const float* We0   = (const float*)d_in[3];
  const float* be0   = (const float*)d_in[4];
  const float* We1   = (const float*)d_in[5];
  const float* be1   = (const float*)d_in[6];
  const float* Wd0   = (const float*)d_in[7];
  const float* bd0   = (const float*)d_in[8];
  const float* Wd1   = (const float*)d_in[9];
  const float* bd1   = (const float*)d_in[10];
  const float* Wd2   = (const float*)d_in[11];
  const float* bd2   = (const float*)d_in[12];
  const float* Wo0   = (const float*)d_in[13];
  const float* bo0   = (const float*)d_in[14];
  const float* Wo1   = (const float*)d_in[15];
  const float* bo1   = (const float*)d_in[16];
  const float* Wih   = (const float*)d_in[17];
  const float* Whh   = (const float*)d_in[18];
  const float* bih   = (const float*)d_in[19];
  const float* bn    = (const float*)d_in[20];

  ode_rnn_kernel<<<dim3(NBATCH), dim3(1024), 0, stream>>>(
      ob, acs, times, We0, be0, We1, be1, Wd0, bd0, Wd1, bd1, Wd2, bd2,
      Wo0, bo0, Wo1, bo1, Wih, Whh, bih, bn, (float*)d_out);
}